// Round 10
// baseline (99.881 us; speedup 1.0000x reference)
//
#include <hip/hip_runtime.h>
#include <hip/hip_bf16.h>
#include <stdint.h>

// L=32, B=8, A=128, D=256, H=8, hd=32, BA=1024, M=32768
// Intermediate layout: qb/kb[b][h][l][a][d]  (d=32 fastest, a=128, l=32)
//   offset = ((bh*32 + l)*128 + a)*32 + d
// vw1/vw2[bh][l][a]; p1[bh][i][j]; p2t[bh][j][i]
// V GEMM eliminated: vw = X @ u, u[k][h] = sum_d Wv[k][h*32+d]*Watt[...]

typedef float f32x4 __attribute__((ext_vector_type(4)));
typedef short s16x8 __attribute__((ext_vector_type(8)));
typedef unsigned short u16x8 __attribute__((ext_vector_type(8)));
typedef unsigned short u16x4 __attribute__((ext_vector_type(4)));

#define EXPC 0.09016844f   // (1/16) * log2(e)

__device__ __forceinline__ unsigned short f2bf(float f) {
  __hip_bfloat16 h = __float2bfloat16(f);
  return __builtin_bit_cast(unsigned short, h);
}
__device__ __forceinline__ f32x4 mfma16(s16x8 a, s16x8 b, f32x4 c) {
  return __builtin_amdgcn_mfma_f32_16x16x32_bf16(a, b, c, 0, 0, 0);
}

// K0: wt[s][n][k] = bf16(W_s[k][n]) for s in {0=Wq,1=Wk};
//     ut[n][k]: n<8 -> u1 per h, n>=8 -> u2 per h
__global__ void wt_kernel(const float* __restrict__ wq, const float* __restrict__ wk,
                          const float* __restrict__ wv, const float* __restrict__ watt,
                          unsigned short* __restrict__ wt, unsigned short* __restrict__ ut) {
  int t = blockIdx.x * 256 + threadIdx.x;           // 0..135167
  if (t < 131072) {
    int s = t >> 16; int w = t & 65535;
    int n = w >> 8;  int k = w & 255;
    const float* W = (s == 0) ? wq : wk;
    wt[t] = f2bf(W[k * 256 + n]);
  } else {
    int t2 = t - 131072;                            // 0..4095
    int n = t2 >> 8, k = t2 & 255;
    const float* wvp = wv + k * 256 + (n & 7) * 32;
    const float* wap = watt + (n >= 8 ? 256 : 0) + (n & 7) * 32;
    float s = 0.f;
    #pragma unroll
    for (int d = 0; d < 32; ++d) s += wvp[d] * wap[d];
    ut[t2] = f2bf(s);
  }
}

// K1: qb/kb = X(32768x256) @ W_s; 64-row M-tiles, 512 blocks x 8 waves.
// Wave (s = wid>>2, wn = wid&3) computes acc[4][4] for one GEMM's 64-n chunk
// (128 MFMAs/wave). Epilogue: ts-transpose (stride 280, <=2-way conflicts),
// ts writes s-guarded between full-block barriers, stores use all 512 threads.
// Wave 3 also computes the u-tile -> vw1/vw2 directly.
__global__ __launch_bounds__(512, 3) void proj_kernel(
    const float* __restrict__ X, const unsigned short* __restrict__ wt,
    const unsigned short* __restrict__ ut,
    unsigned short* __restrict__ qb, unsigned short* __restrict__ kb,
    float* __restrict__ vw1, float* __restrict__ vw2) {
  __shared__ unsigned short xs[64][256];   // 32 KiB input staging (granule XOR swizzle)
  __shared__ unsigned short ts[32][280];   // transpose buffer [a][n], stride 280
  const int tid = threadIdx.x;
  const int bid = blockIdx.x;              // 512
  const int m0 = bid * 64;
  const int l = bid >> 4, b = (bid >> 1) & 7, a0 = (bid & 1) * 64;

  #pragma unroll
  for (int kq = 0; kq < 4; ++kq) {
    int t = tid + kq * 512;
    int row = t >> 5, gc = t & 31;
    const float* src = X + (size_t)(m0 + row) * 256 + gc * 8;
    f32x4 f0 = *(const f32x4*)src;
    f32x4 f1 = *(const f32x4*)(src + 4);
    u16x8 o;
    #pragma unroll
    for (int e = 0; e < 4; ++e) { o[e] = f2bf(f0[e]); o[4 + e] = f2bf(f1[e]); }
    *(u16x8*)&xs[row][(gc ^ (row & 7)) * 8] = o;
  }
  __syncthreads();

  const int wid = tid >> 6, lane = tid & 63;
  const int row16 = lane & 15, grp = lane >> 4;
  const int s = wid >> 2, wn = wid & 3;

  f32x4 acc[4][4];
  #pragma unroll
  for (int mi = 0; mi < 4; ++mi)
    #pragma unroll
    for (int ni = 0; ni < 4; ++ni) acc[mi][ni] = (f32x4){0.f, 0.f, 0.f, 0.f};

  const unsigned short* wbase = wt + s * 65536 + (size_t)(wn * 64 + row16) * 256 + grp * 8;
  #pragma unroll
  for (int kk = 0; kk < 8; ++kk) {
    const int xc = ((kk * 4 + grp) ^ (row16 & 7)) * 8;
    s16x8 xf[4];
    #pragma unroll
    for (int mi = 0; mi < 4; ++mi)
      xf[mi] = *(const s16x8*)&xs[mi * 16 + row16][xc];
    s16x8 wf[4];
    #pragma unroll
    for (int ni = 0; ni < 4; ++ni)
      wf[ni] = *(const s16x8*)(wbase + kk * 32 + ni * 4096);   // A = W rows (n)
    #pragma unroll
    for (int mi = 0; mi < 4; ++mi)
      #pragma unroll
      for (int ni = 0; ni < 4; ++ni)
        acc[mi][ni] = mfma16(wf[ni], xf[mi], acc[mi][ni]);
  }

  // u-tile: wave 3 computes vw1/vw2 for this block's 64 agents.
  if (wid == 3) {
    const f32x4 zero = {0.f, 0.f, 0.f, 0.f};
    f32x4 au[4] = {zero, zero, zero, zero};
    #pragma unroll
    for (int kk = 0; kk < 8; ++kk) {
      const int xc = ((kk * 4 + grp) ^ (row16 & 7)) * 8;
      s16x8 uf = *(const s16x8*)(ut + row16 * 256 + kk * 32 + grp * 8);  // A = u rows (n)
      #pragma unroll
      for (int mi = 0; mi < 4; ++mi) {
        s16x8 xf = *(const s16x8*)&xs[mi * 16 + row16][xc];
        au[mi] = mfma16(uf, xf, au[mi]);
      }
    }
    // lane holds D[row = n = grp*4+r][col = a-sub = row16]
    #pragma unroll
    for (int mi = 0; mi < 4; ++mi)
      #pragma unroll
      for (int r = 0; r < 4; ++r) {
        int n = grp * 4 + r;
        float* dstv = (n < 8) ? vw1 : vw2;
        int h = n & 7;
        dstv[(size_t)(b * 8 + h) * 4096 + l * 128 + a0 + mi * 16 + row16] = au[mi][r];
      }
  }

  // epilogue: per (s2, hh): group-s2 waves write ts; all threads store densely.
  for (int s2 = 0; s2 < 2; ++s2) {
    unsigned short* dst = (s2 == 0) ? qb : kb;
    #pragma unroll
    for (int hh = 0; hh < 2; ++hh) {
      __syncthreads();   // previous ts reads complete
      if (s == s2) {
        #pragma unroll
        for (int mi2 = 0; mi2 < 2; ++mi2)
          #pragma unroll
          for (int ni = 0; ni < 4; ++ni) {
            u16x4 pk;
            #pragma unroll
            for (int r = 0; r < 4; ++r) pk[r] = f2bf(acc[hh * 2 + mi2][ni][r]);
            *(u16x4*)&ts[mi2 * 16 + row16][wn * 64 + ni * 16 + grp * 4] = pk;
          }
      }
      __syncthreads();
      #pragma unroll
      for (int q = 0; q < 2; ++q) {
        int u = tid + q * 512;
        int dg = u & 3;
        int a = (u >> 2) & 31;
        int h = u >> 7;
        u16x8 g8 = *(const u16x8*)&ts[a][h * 32 + dg * 8];
        size_t off = (((size_t)(b * 8 + h) * 32 + l) * 128 + a0 + hh * 32 + a) * 32 + dg * 8;
        *(u16x8*)(dst + off) = g8;
      }
    }
  }
}

// K2 (round-7 verbatim): single-pass. Block = (bh, it, jh), 4 waves, jt = jh*4+w.
// mfma(K,Q): lane holds i = it*16+g*4+r (r=0..3), j = jt*16+r16, all 32 l in regs.
// Softmax + p-dots lane-local. Stores bounce through wave-private LDS so each
// global store is a fully-dense 1KB dwordx4.
__global__ __launch_bounds__(256, 2) void attn_kernel(
    const unsigned short* __restrict__ qb, const unsigned short* __restrict__ kb,
    const float* __restrict__ vw1, const float* __restrict__ vw2,
    float* __restrict__ attn_out, float* __restrict__ p1, float* __restrict__ p2t) {
  __shared__ float ls[4][8][64][4];            // 32 KiB; [wave][lq][pair][e]
  const int bid = blockIdx.x;                  // 1024 = 64 bh * 8 it * 2 jh
  const int swz = (bid & 7) * 128 + (bid >> 3);
  const int bh = swz >> 4, it = (swz >> 1) & 7, jh = swz & 1;
  const int tid = threadIdx.x;
  const int w = tid >> 6, lane = tid & 63;
  const int r16 = lane & 15, g = lane >> 4;
  const int jt = jh * 4 + w;

  const unsigned short* kp = kb + (size_t)bh * 131072 + (it * 16 + r16) * 32 + g * 8;
  const unsigned short* qp = qb + (size_t)bh * 131072 + (jt * 16 + r16) * 32 + g * 8;
  const float* vp1 = vw1 + bh * 4096 + it * 16 + g * 4;
  const float* vp2 = vw2 + bh * 4096 + it * 16 + g * 4;
  const f32x4 zero = {0.f, 0.f, 0.f, 0.f};

  // scores: acc[l][r] for lane's 4 (i,j) pairs
  f32x4 acc[32];
  #pragma unroll
  for (int l = 0; l < 32; ++l) {
    s16x8 kf = *(const s16x8*)(kp + l * 4096);
    s16x8 qf = *(const s16x8*)(qp + l * 4096);
    acc[l] = mfma16(kf, qf, zero);
  }

  // exp + sums + p-dots (pre-normalization)
  float sum[4] = {0.f, 0.f, 0.f, 0.f};
  float t1[4] = {0.f, 0.f, 0.f, 0.f}, t2[4] = {0.f, 0.f, 0.f, 0.f};
  #pragma unroll
  for (int l = 0; l < 32; ++l) {
    f32x4 v1 = *(const f32x4*)(vp1 + l * 128);
    f32x4 v2 = *(const f32x4*)(vp2 + l * 128);
    #pragma unroll
    for (int r = 0; r < 4; ++r) {
      float e = exp2f(acc[l][r] * EXPC);
      acc[l][r] = e;
      sum[r] += e;
      t1[r] += e * v1[r];
      t2[r] += e * v2[r];
    }
  }

  #pragma unroll
  for (int r = 0; r < 4; ++r) {
    const float inv = 1.f / sum[r];
    const int i = it * 16 + g * 4 + r, j = jt * 16 + r16;
    p1[(size_t)bh * 16384 + i * 128 + j] = t1[r] * inv;
    p2t[(size_t)bh * 16384 + j * 128 + i] = t2[r] * inv;

    // write this r's 64 (i,j) rows (128B each) to LDS
    #pragma unroll
    for (int lq = 0; lq < 8; ++lq) {
      f32x4 w4;
      #pragma unroll
      for (int e = 0; e < 4; ++e) w4[e] = acc[lq * 4 + e][r] * inv;
      *(f32x4*)&ls[w][lq][lane][0] = w4;
    }
    // read back coalesced; 8 dense 1KB stores
    #pragma unroll
    for (int t = 0; t < 8; ++t) {
      const int i_idx = t >> 1, half = t & 1;
      f32x4 d = *(const f32x4*)&ls[w][lane & 7][i_idx * 16 + half * 8 + (lane >> 3)][0];
      float* dst = attn_out + ((size_t)bh * 128 + it * 16 + i_idx * 4 + r) * 4096
                   + jt * 512 + half * 256 + lane * 4;
      *(f32x4*)dst = d;
    }
  }
}

// K3: weight[b,i,j] = tanh(sum_h p1[b,h,i,j] + sum_h p2t[b,h,i,j] + b_att + 0.5) * (i!=j)
__global__ void weight_kernel(const float* __restrict__ p1, const float* __restrict__ p2t,
                              const float* __restrict__ b_att, float* __restrict__ wout) {
  int t = blockIdx.x * 256 + threadIdx.x;   // 0..131071
  int b = t >> 14, ij = t & 16383, i = ij >> 7, j = ij & 127;
  float s = b_att[0] + 0.5f;
  #pragma unroll
  for (int h = 0; h < 8; ++h) {
    s += p1[((size_t)(b * 8 + h) * 16384) + ij];
    s += p2t[((size_t)(b * 8 + h) * 16384) + ij];
  }
  float w = tanhf(s);
  wout[t] = (i == j) ? 0.f : w;
}

extern "C" void kernel_launch(void* const* d_in, const int* in_sizes, int n_in,
                              void* d_out, int out_size, void* d_ws, size_t ws_size,
                              hipStream_t stream) {
  const float* X    = (const float*)d_in[0];   // output (L, B*A, D)
  const float* Wk   = (const float*)d_in[1];
  const float* Wq   = (const float*)d_in[2];
  const float* Wv   = (const float*)d_in[3];
  const float* Watt = (const float*)d_in[4];   // (512,1)
  const float* b_att= (const float*)d_in[5];   // (1,)

  char* ws = (char*)d_ws;
  unsigned short* wt = (unsigned short*)ws;                 // 256 KiB (q,k)
  unsigned short* ut = (unsigned short*)(ws + 262144);      // 8 KiB
  unsigned short* qb = (unsigned short*)(ws + 524288);      // 16 MiB each
  unsigned short* kb = (unsigned short*)(ws + 524288 + 16777216);
  float* vw1 = (float*)(ws + 524288 + 2 * 16777216);        // 1 MiB each
  float* vw2 = (float*)(ws + 524288 + 2 * 16777216 + 1048576);
  float* p1  = (float*)(ws + 524288 + 2 * 16777216 + 2 * 1048576);   // 4 MiB each
  float* p2t = (float*)(ws + 524288 + 2 * 16777216 + 2 * 1048576 + 4194304);

  float* attn_out = (float*)d_out;                    // 33554432 floats
  float* wout     = (float*)d_out + 33554432;         // 131072 floats

  wt_kernel<<<dim3(528), dim3(256), 0, stream>>>(Wq, Wk, Wv, Watt, wt, ut);
  proj_kernel<<<dim3(512), dim3(512), 0, stream>>>(X, wt, ut, qb, kb, vw1, vw2);
  attn_kernel<<<dim3(1024), dim3(256), 0, stream>>>(qb, kb, vw1, vw2, attn_out, p1, p2t);
  weight_kernel<<<dim3(512), dim3(256), 0, stream>>>(p1, p2t, b_att, wout);
}

// Round 11
// 78.323 us; speedup vs baseline: 1.2752x; 1.2752x over previous
//
#include <hip/hip_runtime.h>
#include <hip/hip_bf16.h>
#include <stdint.h>

// L=32, B=8, A=128, D=256, H=8, hd=32, BA=1024, M=32768
// Intermediate layout: qb/kb[b][h][l][a][d]  (d=32 fastest, a=128, l=32)
//   offset = ((bh*32 + l)*128 + a)*32 + d
// vw1/vw2[bh][l][a]; p1[bh][i][j]; p2t[bh][j][i]
// V GEMM eliminated: vw = X @ u, u[k][h] = sum_d Wv[k][h*32+d]*Watt[...]
// ROUND 11: exact re-submission of the round-7 source (78.0 us) for re-baseline.

typedef float f32x4 __attribute__((ext_vector_type(4)));
typedef short s16x8 __attribute__((ext_vector_type(8)));
typedef unsigned short u16x8 __attribute__((ext_vector_type(8)));
typedef unsigned short u16x4 __attribute__((ext_vector_type(4)));

#define EXPC 0.09016844f   // (1/16) * log2(e)

__device__ __forceinline__ unsigned short f2bf(float f) {
  __hip_bfloat16 h = __float2bfloat16(f);
  return __builtin_bit_cast(unsigned short, h);
}
__device__ __forceinline__ f32x4 mfma16(s16x8 a, s16x8 b, f32x4 c) {
  return __builtin_amdgcn_mfma_f32_16x16x32_bf16(a, b, c, 0, 0, 0);
}

// K0: wt[s][n][k] = bf16(W_s[k][n]) for s in {0=Wq,1=Wk};
//     ut[n][k]: n<8 -> u1 per h, n>=8 -> u2 per h
__global__ void wt_kernel(const float* __restrict__ wq, const float* __restrict__ wk,
                          const float* __restrict__ wv, const float* __restrict__ watt,
                          unsigned short* __restrict__ wt, unsigned short* __restrict__ ut) {
  int t = blockIdx.x * 256 + threadIdx.x;           // 0..135167
  if (t < 131072) {
    int s = t >> 16; int w = t & 65535;
    int n = w >> 8;  int k = w & 255;
    const float* W = (s == 0) ? wq : wk;
    wt[t] = f2bf(W[k * 256 + n]);
  } else {
    int t2 = t - 131072;                            // 0..4095
    int n = t2 >> 8, k = t2 & 255;
    const float* wvp = wv + k * 256 + (n & 7) * 32;
    const float* wap = watt + (n >= 8 ? 256 : 0) + (n & 7) * 32;
    float s = 0.f;
    #pragma unroll
    for (int d = 0; d < 32; ++d) s += wvp[d] * wap[d];
    ut[t2] = f2bf(s);
  }
}

// K1: qb/kb = X(32768x256) @ W_s; 64-row M-tiles, 512 blocks x 4 waves.
// Per wave: acc[4][4] f32x4, 16 MFMAs/kk with 4x reuse of wt and xs fragments.
// Transpose epilogue in two 32-row halves (ts stride 280, <=2-way conflicts),
// 16 fully-dense 1KB stores per block per s. Wave 3 also computes u-tile.
__global__ __launch_bounds__(256, 3) void proj_kernel(
    const float* __restrict__ X, const unsigned short* __restrict__ wt,
    const unsigned short* __restrict__ ut,
    unsigned short* __restrict__ qb, unsigned short* __restrict__ kb,
    float* __restrict__ vw1, float* __restrict__ vw2) {
  __shared__ unsigned short xs[64][256];   // 32 KiB input staging (granule XOR swizzle)
  __shared__ unsigned short ts[32][280];   // transpose buffer [a][n], stride 280
  const int tid = threadIdx.x;
  const int bid = blockIdx.x;              // 512
  const int m0 = bid * 64;
  const int l = bid >> 4, b = (bid >> 1) & 7, a0 = (bid & 1) * 64;

  #pragma unroll
  for (int kq = 0; kq < 8; ++kq) {
    int t = tid + kq * 256;
    int row = t >> 5, gc = t & 31;
    const float* src = X + (size_t)(m0 + row) * 256 + gc * 8;
    f32x4 f0 = *(const f32x4*)src;
    f32x4 f1 = *(const f32x4*)(src + 4);
    u16x8 o;
    #pragma unroll
    for (int e = 0; e < 4; ++e) { o[e] = f2bf(f0[e]); o[4 + e] = f2bf(f1[e]); }
    *(u16x8*)&xs[row][(gc ^ (row & 7)) * 8] = o;
  }
  __syncthreads();

  const int wid = tid >> 6, lane = tid & 63;
  const int row16 = lane & 15, grp = lane >> 4;
  const int wn = wid;  // n-chunk of 64

  for (int s = 0; s < 2; ++s) {
    f32x4 acc[4][4];
    #pragma unroll
    for (int mi = 0; mi < 4; ++mi)
      #pragma unroll
      for (int ni = 0; ni < 4; ++ni) acc[mi][ni] = (f32x4){0.f, 0.f, 0.f, 0.f};

    const unsigned short* wbase = wt + s * 65536 + (size_t)(wn * 64 + row16) * 256 + grp * 8;
    #pragma unroll
    for (int kk = 0; kk < 8; ++kk) {
      const int xc = ((kk * 4 + grp) ^ (row16 & 7)) * 8;
      s16x8 xf[4];
      #pragma unroll
      for (int mi = 0; mi < 4; ++mi)
        xf[mi] = *(const s16x8*)&xs[mi * 16 + row16][xc];
      s16x8 wf[4];
      #pragma unroll
      for (int ni = 0; ni < 4; ++ni)
        wf[ni] = *(const s16x8*)(wbase + kk * 32 + ni * 4096);   // A = W rows (n)
      #pragma unroll
      for (int mi = 0; mi < 4; ++mi)
        #pragma unroll
        for (int ni = 0; ni < 4; ++ni)
          acc[mi][ni] = mfma16(wf[ni], xf[mi], acc[mi][ni]);
    }

    unsigned short* dst = (s == 0) ? qb : kb;
    #pragma unroll
    for (int hh = 0; hh < 2; ++hh) {
      __syncthreads();   // previous ts reads complete
      #pragma unroll
      for (int mi2 = 0; mi2 < 2; ++mi2)
        #pragma unroll
        for (int ni = 0; ni < 4; ++ni) {
          u16x4 pk;
          #pragma unroll
          for (int r = 0; r < 4; ++r) pk[r] = f2bf(acc[hh * 2 + mi2][ni][r]);
          *(u16x4*)&ts[mi2 * 16 + row16][wn * 64 + ni * 16 + grp * 4] = pk;
        }
      __syncthreads();
      #pragma unroll
      for (int q = 0; q < 4; ++q) {
        int h = q * 2 + (tid >> 7);
        int a = (tid >> 2) & 31;
        int dg = tid & 3;
        u16x8 g8 = *(const u16x8*)&ts[a][h * 32 + dg * 8];
        size_t off = (((size_t)(b * 8 + h) * 32 + l) * 128 + a0 + hh * 32 + a) * 32 + dg * 8;
        *(u16x8*)(dst + off) = g8;
      }
    }
  }

  // u-tile: wave 3 computes vw1/vw2 for this block's 64 agents.
  if (wid == 3) {
    const f32x4 zero = {0.f, 0.f, 0.f, 0.f};
    f32x4 au[4] = {zero, zero, zero, zero};
    #pragma unroll
    for (int kk = 0; kk < 8; ++kk) {
      const int xc = ((kk * 4 + grp) ^ (row16 & 7)) * 8;
      s16x8 uf = *(const s16x8*)(ut + row16 * 256 + kk * 32 + grp * 8);  // A = u rows (n)
      #pragma unroll
      for (int mi = 0; mi < 4; ++mi) {
        s16x8 xf = *(const s16x8*)&xs[mi * 16 + row16][xc];
        au[mi] = mfma16(uf, xf, au[mi]);
      }
    }
    // lane holds D[row = n = grp*4+r][col = a-sub = row16]
    #pragma unroll
    for (int mi = 0; mi < 4; ++mi)
      #pragma unroll
      for (int r = 0; r < 4; ++r) {
        int n = grp * 4 + r;
        float* dstv = (n < 8) ? vw1 : vw2;
        int h = n & 7;
        dstv[(size_t)(b * 8 + h) * 4096 + l * 128 + a0 + mi * 16 + row16] = au[mi][r];
      }
  }
}

// K2: single-pass. Block = (bh, it, jh), 4 waves, wave w -> jt = jh*4+w.
// mfma(K,Q): lane holds i = it*16+g*4+r (r=0..3), j = jt*16+r16, all 32 l in regs.
// Softmax + p-dots lane-local. Stores bounce through wave-private LDS so each
// global store is a fully-dense 1KB dwordx4.
__global__ __launch_bounds__(256, 2) void attn_kernel(
    const unsigned short* __restrict__ qb, const unsigned short* __restrict__ kb,
    const float* __restrict__ vw1, const float* __restrict__ vw2,
    float* __restrict__ attn_out, float* __restrict__ p1, float* __restrict__ p2t) {
  __shared__ float ls[4][8][64][4];            // 32 KiB; [wave][lq][pair][e]
  const int bid = blockIdx.x;                  // 1024 = 64 bh * 8 it * 2 jh
  const int swz = (bid & 7) * 128 + (bid >> 3);
  const int bh = swz >> 4, it = (swz >> 1) & 7, jh = swz & 1;
  const int tid = threadIdx.x;
  const int w = tid >> 6, lane = tid & 63;
  const int r16 = lane & 15, g = lane >> 4;
  const int jt = jh * 4 + w;

  const unsigned short* kp = kb + (size_t)bh * 131072 + (it * 16 + r16) * 32 + g * 8;
  const unsigned short* qp = qb + (size_t)bh * 131072 + (jt * 16 + r16) * 32 + g * 8;
  const float* vp1 = vw1 + bh * 4096 + it * 16 + g * 4;
  const float* vp2 = vw2 + bh * 4096 + it * 16 + g * 4;
  const f32x4 zero = {0.f, 0.f, 0.f, 0.f};

  // scores: acc[l][r] for lane's 4 (i,j) pairs
  f32x4 acc[32];
  #pragma unroll
  for (int l = 0; l < 32; ++l) {
    s16x8 kf = *(const s16x8*)(kp + l * 4096);
    s16x8 qf = *(const s16x8*)(qp + l * 4096);
    acc[l] = mfma16(kf, qf, zero);
  }

  // exp + sums + p-dots (pre-normalization)
  float sum[4] = {0.f, 0.f, 0.f, 0.f};
  float t1[4] = {0.f, 0.f, 0.f, 0.f}, t2[4] = {0.f, 0.f, 0.f, 0.f};
  #pragma unroll
  for (int l = 0; l < 32; ++l) {
    f32x4 v1 = *(const f32x4*)(vp1 + l * 128);
    f32x4 v2 = *(const f32x4*)(vp2 + l * 128);
    #pragma unroll
    for (int r = 0; r < 4; ++r) {
      float e = exp2f(acc[l][r] * EXPC);
      acc[l][r] = e;
      sum[r] += e;
      t1[r] += e * v1[r];
      t2[r] += e * v2[r];
    }
  }

  #pragma unroll
  for (int r = 0; r < 4; ++r) {
    const float inv = 1.f / sum[r];
    const int i = it * 16 + g * 4 + r, j = jt * 16 + r16;
    p1[(size_t)bh * 16384 + i * 128 + j] = t1[r] * inv;
    p2t[(size_t)bh * 16384 + j * 128 + i] = t2[r] * inv;

    // write this r's 64 (i,j) rows (128B each) to LDS
    #pragma unroll
    for (int lq = 0; lq < 8; ++lq) {
      f32x4 w4;
      #pragma unroll
      for (int e = 0; e < 4; ++e) w4[e] = acc[lq * 4 + e][r] * inv;
      *(f32x4*)&ls[w][lq][lane][0] = w4;
    }
    // read back coalesced; 8 dense 1KB stores
    #pragma unroll
    for (int t = 0; t < 8; ++t) {
      const int i_idx = t >> 1, half = t & 1;
      f32x4 d = *(const f32x4*)&ls[w][lane & 7][i_idx * 16 + half * 8 + (lane >> 3)][0];
      float* dst = attn_out + ((size_t)bh * 128 + it * 16 + i_idx * 4 + r) * 4096
                   + jt * 512 + half * 256 + lane * 4;
      *(f32x4*)dst = d;
    }
  }
}

// K3: weight[b,i,j] = tanh(sum_h p1[b,h,i,j] + sum_h p2t[b,h,i,j] + b_att + 0.5) * (i!=j)
__global__ void weight_kernel(const float* __restrict__ p1, const float* __restrict__ p2t,
                              const float* __restrict__ b_att, float* __restrict__ wout) {
  int t = blockIdx.x * 256 + threadIdx.x;   // 0..131071
  int b = t >> 14, ij = t & 16383, i = ij >> 7, j = ij & 127;
  float s = b_att[0] + 0.5f;
  #pragma unroll
  for (int h = 0; h < 8; ++h) {
    s += p1[((size_t)(b * 8 + h) * 16384) + ij];
    s += p2t[((size_t)(b * 8 + h) * 16384) + ij];
  }
  float w = tanhf(s);
  wout[t] = (i == j) ? 0.f : w;
}

extern "C" void kernel_launch(void* const* d_in, const int* in_sizes, int n_in,
                              void* d_out, int out_size, void* d_ws, size_t ws_size,
                              hipStream_t stream) {
  const float* X    = (const float*)d_in[0];   // output (L, B*A, D)
  const float* Wk   = (const float*)d_in[1];
  const float* Wq   = (const float*)d_in[2];
  const float* Wv   = (const float*)d_in[3];
  const float* Watt = (const float*)d_in[4];   // (512,1)
  const float* b_att= (const float*)d_in[5];   // (1,)

  char* ws = (char*)d_ws;
  unsigned short* wt = (unsigned short*)ws;                 // 256 KiB (q,k)
  unsigned short* ut = (unsigned short*)(ws + 262144);      // 8 KiB
  unsigned short* qb = (unsigned short*)(ws + 524288);      // 16 MiB each
  unsigned short* kb = (unsigned short*)(ws + 524288 + 16777216);
  float* vw1 = (float*)(ws + 524288 + 2 * 16777216);        // 1 MiB each
  float* vw2 = (float*)(ws + 524288 + 2 * 16777216 + 1048576);
  float* p1  = (float*)(ws + 524288 + 2 * 16777216 + 2 * 1048576);   // 4 MiB each
  float* p2t = (float*)(ws + 524288 + 2 * 16777216 + 2 * 1048576 + 4194304);

  float* attn_out = (float*)d_out;                    // 33554432 floats
  float* wout     = (float*)d_out + 33554432;         // 131072 floats

  wt_kernel<<<dim3(528), dim3(256), 0, stream>>>(Wq, Wk, Wv, Watt, wt, ut);
  proj_kernel<<<dim3(512), dim3(256), 0, stream>>>(X, wt, ut, qb, kb, vw1, vw2);
  attn_kernel<<<dim3(1024), dim3(256), 0, stream>>>(qb, kb, vw1, vw2, attn_out, p1, p2t);
  weight_kernel<<<dim3(512), dim3(256), 0, stream>>>(p1, p2t, b_att, wout);
}